// Round 19
// baseline (87.245 us; speedup 1.0000x reference)
//
#include <hip/hip_runtime.h>

// ---------------------------------------------------------------------------
// DWT autoencoder round trip. Level-2 dwt2+idwt2 cancel exactly -> LL1r==LL1.
//   K0: rearrange conv weights into consumption order
//   K1: R18's verified skeleton (band planes in 20.2KB LDS, one barrier,
//       og-split conv) with VMEM WIDENED: stage = float4 pairs (2 band cols
//       per item), LL1 = float2 stores. VMEM instr/block 6054 -> 3654.
//       Theory: CU vector-mem path issues ~1 wave-instr/cycle regardless of
//       width; k1 has been VMEM-ISSUE-COUNT bound all along (k2 at 48k
//       instr/CU = 20us, k1-R18 at 87k = 57us; occupancy 19->72% changed
//       nothing, staging mechanism changed nothing).
//   K2: convT4x4 s2 of y -> l1 bands, fused with idwt2(LL1, l1) -> out
// B=32, C=3, H=W=512.
// ---------------------------------------------------------------------------

#define BB 32

// K0: wd[(cin*9 + a*3 + q)*9 + o] = 0.5 * dw[o, cin, a, q]   (cin = ch*3+band)
//     wu[((cin*4+rt*2+ct)*4+di*2+dj)*9+o] = uw[cin, o, 3-di-2rt, 3-dj-2ct]
__global__ __launch_bounds__(256) void k0_rearrange(
    const float* __restrict__ dw, const float* __restrict__ uw,
    float* __restrict__ wd, float* __restrict__ wu)
{
    const int t = threadIdx.x;
    for (int i = t; i < 729; i += 256) {
        const int o   = i % 9;
        const int q   = (i / 9) % 3;
        const int a   = (i / 27) % 3;
        const int cin = i / 81;
        wd[i] = 0.5f * dw[o * 81 + cin * 9 + a * 3 + q];
    }
    for (int i = t; i < 1296; i += 256) {
        const int o = i % 9; int r = i / 9;
        const int dj = r & 1; const int di = (r >> 1) & 1; r >>= 2;
        const int ct = r & 1; const int rt = (r >> 1) & 1; const int cin = r >> 2;
        wu[i] = uw[cin * 144 + o * 16 + (3 - di - 2 * rt) * 4 + (3 - dj - 2 * ct)];
    }
}

// K1: block = 8x16 y-tile. Band grid 17x33 per (ch,band), LDS stride 33.
// Main stage items: (ch, lr, m) = 3x17x16 = 816; each loads 2 float4
// (x rows 2rB, 2rB+1, cols 4J0+4m..+3) -> band cols c_loc = 2m+1, 2m+2,
// + one float2 LL1 store (cols 2J0+2m, +1) for lr>=1.
// Edge items (c_loc=0): 51, one float2 pair each (left halo; zero at J0==0).
// One barrier, then R18's verified og-split conv.
__global__ __launch_bounds__(256) void k1_dwt_down(
    const float* __restrict__ x,     // (B,3,512,512)
    const float* __restrict__ wd,    // reordered (cin,a,q,o), x0.5 folded
    const float* __restrict__ db,    // (9)
    float* __restrict__ LL1,         // (B,3,256,256)
    float* __restrict__ y)           // (B,9,128,128)
{
    __shared__ float bnd[9 * 561];   // plane (ch*3+band): 17 x 33, 20.2 KB

    const int t   = threadIdx.x;
    const int bid = blockIdx.x;                     // 0..4095
    const int swz = (bid & 7) * 512 + (bid >> 3);   // XCD-contiguous chunks
    const int b   = swz >> 7;                       // image 0..31
    const int tin = swz & 127;
    const int I0  = (tin >> 3) * 8;                 // y row origin (0..120)
    const int J0  = (tin & 7) * 16;                 // y col origin (0..112)

    // ---- stage main: 816 items, 2x float4 each ----
    for (int it = t; it < 816; it += 256) {
        const int ch = it / 272;
        const int rc = it - ch * 272;
        const int lr = rc >> 4;                     // 0..16
        const int m  = rc & 15;                     // 0..15
        const int rB = 2 * I0 - 1 + lr;             // band row, -1..254
        float4 A = make_float4(0.f, 0.f, 0.f, 0.f);
        float4 Bv = make_float4(0.f, 0.f, 0.f, 0.f);
        if (rB >= 0) {
            const float* xp =
                x + (((size_t)b * 3 + ch) * 512 + 2 * rB) * 512 + 4 * J0 + 4 * m;
            A  = *reinterpret_cast<const float4*>(xp);
            Bv = *reinterpret_cast<const float4*>(xp + 512);
        }
        float* pl = &bnd[ch * 3 * 561 + lr * 33 + 2 * m + 1];
        float ll0, ll1;
        {   // c_loc = 2m+1
            const float s0 = A.x + A.y, d0 = A.x - A.y;
            const float s1 = Bv.x + Bv.y, d1 = Bv.x - Bv.y;
            pl[0]        = s0 - s1;                  // lh
            pl[561]      = d0 + d1;                  // hl
            pl[1122]     = d0 - d1;                  // hh
            ll0 = (s0 + s1) * 0.5f;
        }
        {   // c_loc = 2m+2
            const float s0 = A.z + A.w, d0 = A.z - A.w;
            const float s1 = Bv.z + Bv.w, d1 = Bv.z - Bv.w;
            pl[1]        = s0 - s1;
            pl[562]      = d0 + d1;
            pl[1123]     = d0 - d1;
            ll1 = (s0 + s1) * 0.5f;
        }
        if (lr >= 1) {
            float2 w2; w2.x = ll0; w2.y = ll1;
            *reinterpret_cast<float2*>(
                LL1 + (((size_t)b * 3 + ch) * 256 + rB) * 256 + 2 * J0 + 2 * m) = w2;
        }
    }
    // ---- stage edge: c_loc = 0 column (51 items) ----
    if (t < 51) {
        const int ch = t / 17;
        const int lr = t - ch * 17;
        const int rB = 2 * I0 - 1 + lr;
        float2 a2 = make_float2(0.f, 0.f), b2 = make_float2(0.f, 0.f);
        if (rB >= 0 && J0 > 0) {
            const float* xp =
                x + (((size_t)b * 3 + ch) * 512 + 2 * rB) * 512 + 4 * J0 - 2;
            a2 = *reinterpret_cast<const float2*>(xp);
            b2 = *reinterpret_cast<const float2*>(xp + 512);
        }
        const float s0 = a2.x + a2.y, d0 = a2.x - a2.y;
        const float s1 = b2.x + b2.y, d1 = b2.x - b2.y;
        bnd[(ch * 3 + 0) * 561 + lr * 33] = s0 - s1;
        bnd[(ch * 3 + 1) * 561 + lr * 33] = d0 + d1;
        bnd[(ch * 3 + 2) * 561 + lr * 33] = d0 - d1;
        // c_loc=0 ll (col 2J0-1) is owned by the tile to the left; no store
    }
    __syncthreads();

    // ---- conv: R18's verified og-split (9 cin, 9 ds_reads, uniform weights) ----
    const int og = t >> 7;           // wave-uniform output half
    const int tl = t & 127;
    const int ti = tl >> 4;          // 0..7
    const int tj = tl & 15;          // 0..15
    const int I  = I0 + ti;
    const int J  = J0 + tj;

    if (og == 0) {
        float acc[5];
#pragma unroll
        for (int o = 0; o < 5; ++o) acc[o] = db[o];
        for (int cin = 0; cin < 9; ++cin) {
            float v[3][3];
#pragma unroll
            for (int a = 0; a < 3; ++a)
#pragma unroll
                for (int q = 0; q < 3; ++q)
                    v[a][q] = bnd[cin * 561 + (2 * ti + a) * 33 + 2 * tj + q];
            const float* wc = wd + cin * 81;
#pragma unroll
            for (int a = 0; a < 3; ++a)
#pragma unroll
                for (int q = 0; q < 3; ++q) {
                    const float vv = v[a][q];
                    const float* w9 = wc + (a * 3 + q) * 9;
#pragma unroll
                    for (int o = 0; o < 5; ++o) acc[o] += vv * w9[o];
                }
        }
#pragma unroll
        for (int o = 0; o < 5; ++o)
            y[(((size_t)b * 9 + o) * 128 + I) * 128 + J] = acc[o];
    } else {
        float acc[4];
#pragma unroll
        for (int o = 0; o < 4; ++o) acc[o] = db[5 + o];
        for (int cin = 0; cin < 9; ++cin) {
            float v[3][3];
#pragma unroll
            for (int a = 0; a < 3; ++a)
#pragma unroll
                for (int q = 0; q < 3; ++q)
                    v[a][q] = bnd[cin * 561 + (2 * ti + a) * 33 + 2 * tj + q];
            const float* wc = wd + cin * 81;
#pragma unroll
            for (int a = 0; a < 3; ++a)
#pragma unroll
                for (int q = 0; q < 3; ++q) {
                    const float vv = v[a][q];
                    const float* w9 = wc + (a * 3 + q) * 9 + 5;
#pragma unroll
                    for (int o = 0; o < 4; ++o) acc[o] += vv * w9[o];
                }
        }
#pragma unroll
        for (int o = 0; o < 4; ++o)
            y[(((size_t)b * 9 + 5 + o) * 128 + I) * 128 + J] = acc[o];
    }
}

// K2: one block = one batch image, a 32x32 tile at 256-res (=> 64x64 output
// pixels at 512-res), all 3 colors. Each thread owns a 2x2 parity quad; all
// 36 accumulators live (needs VGPR room -> launch_bounds(256,4)).
__global__ __launch_bounds__(256, 4) void k2_up_idwt(
    const float* __restrict__ yg,    // (B,9,128,128)
    const float* __restrict__ wu,    // reordered (cin,rt,ct,di,dj,o)
    const float* __restrict__ ub,    // (9)
    const float* __restrict__ LL1,   // (B,3,256,256)
    float* __restrict__ out)         // (B,3,512,512)
{
    __shared__ float ysh[9][18][19];

    const int t    = threadIdx.x;
    const int b    = blockIdx.x >> 6;
    const int tile = blockIdx.x & 63;
    const int r0   = (tile >> 3) << 5;  // 256-res tile origin
    const int c0   = (tile & 7) << 5;
    const int p0   = (r0 >> 1) - 1;     // y row of local 0
    const int q0   = (c0 >> 1) - 1;

    // ---- stage y tile (18x18 halo, 9 ch) into LDS ----
    for (int item = t; item < 9 * 324; item += 256) {
        const int cin = item / 324;
        int rem       = item - cin * 324;
        const int lp  = rem / 18;
        const int lq  = rem - lp * 18;
        const int p   = p0 + lp, q = q0 + lq;
        float v = 0.f;
        if (p >= 0 && p < 128 && q >= 0 && q < 128)
            v = yg[(((size_t)b * 9 + cin) * 128 + p) * 128 + q];
        ysh[cin][lp][lq] = v;
    }
    __syncthreads();

    const int i2 = t >> 4;   // 0..15
    const int j2 = t & 15;   // 0..15

    float acc[2][2][9];      // [di][dj][out-ch]
#pragma unroll
    for (int di = 0; di < 2; ++di)
#pragma unroll
        for (int dj = 0; dj < 2; ++dj)
#pragma unroll
            for (int o = 0; o < 9; ++o) acc[di][dj][o] = ub[o];

    for (int cin = 0; cin < 9; ++cin) {
        float yv[3][3];
#pragma unroll
        for (int r = 0; r < 3; ++r)
#pragma unroll
            for (int c = 0; c < 3; ++c)
                yv[r][c] = ysh[cin][i2 + r][j2 + c];
        const float* wc = wu + cin * 144;
#pragma unroll
        for (int rt = 0; rt < 2; ++rt)
#pragma unroll
            for (int ct = 0; ct < 2; ++ct) {
                const float* wg = wc + (rt * 2 + ct) * 36;  // 36 consecutive
#pragma unroll
                for (int di = 0; di < 2; ++di)
#pragma unroll
                    for (int dj = 0; dj < 2; ++dj) {
                        const float vv = yv[di + rt][dj + ct];
                        const float* w9 = wg + (di * 2 + dj) * 9;
#pragma unroll
                        for (int o = 0; o < 9; ++o)
                            acc[di][dj][o] += vv * w9[o];
                    }
            }
    }

    // ---- epilogue: idwt2(LL1, LH, HL, HH) -> 4x4 output pixels / color ----
#pragma unroll
    for (int cc = 0; cc < 3; ++cc) {
#pragma unroll
        for (int di = 0; di < 2; ++di) {
            const int I = r0 + 2 * i2 + di;
            const int J = c0 + 2 * j2;
            const float2 llv = *reinterpret_cast<const float2*>(
                LL1 + (((size_t)b * 3 + cc) * 256 + I) * 256 + J);
            float4 top, bot;
            {
                const float ll = llv.x;
                const float lh = acc[di][0][cc * 3 + 0];
                const float hl = acc[di][0][cc * 3 + 1];
                const float hh = acc[di][0][cc * 3 + 2];
                const float e0 = ll + lh, od0 = ll - lh;
                const float e1 = hl + hh, od1 = hl - hh;
                top.x = (e0 + e1) * 0.5f; top.y = (e0 - e1) * 0.5f;
                bot.x = (od0 + od1) * 0.5f; bot.y = (od0 - od1) * 0.5f;
            }
            {
                const float ll = llv.y;
                const float lh = acc[di][1][cc * 3 + 0];
                const float hl = acc[di][1][cc * 3 + 1];
                const float hh = acc[di][1][cc * 3 + 2];
                const float e0 = ll + lh, od0 = ll - lh;
                const float e1 = hl + hh, od1 = hl - hh;
                top.z = (e0 + e1) * 0.5f; top.w = (e0 - e1) * 0.5f;
                bot.z = (od0 + od1) * 0.5f; bot.w = (od0 - od1) * 0.5f;
            }
            float* op = out + (((size_t)b * 3 + cc) * 512 + 2 * I) * 512 + 2 * J;
            *reinterpret_cast<float4*>(op) = top;
            *reinterpret_cast<float4*>(op + 512) = bot;
        }
    }
}

extern "C" void kernel_launch(void* const* d_in, const int* in_sizes, int n_in,
                              void* d_out, int out_size, void* d_ws, size_t ws_size,
                              hipStream_t stream) {
    const float* x  = (const float*)d_in[0];
    const float* dw = (const float*)d_in[1];
    const float* db = (const float*)d_in[2];
    const float* uw = (const float*)d_in[3];
    const float* ub = (const float*)d_in[4];
    float* outp = (float*)d_out;

    float* wsf = (float*)d_ws;
    float* wd  = wsf;            // 729 floats (pad to 768)
    float* wu  = wsf + 768;      // 1296 floats
    float* LL1 = wsf + 2304;                         // 25.2 MB
    float* y   = LL1 + (size_t)BB * 3 * 256 * 256;   // 18.9 MB

    k0_rearrange<<<dim3(1), dim3(256), 0, stream>>>(dw, uw, wd, wu);
    k1_dwt_down<<<dim3(4096), dim3(256), 0, stream>>>(x, wd, db, LL1, y);
    k2_up_idwt<<<dim3(BB * 64), dim3(256), 0, stream>>>(y, wu, ub, LL1, outp);
}